// Round 4
// baseline (7394.583 us; speedup 1.0000x reference)
//
#include <hip/hip_runtime.h>
#include <hip/hip_bf16.h>
#include <stdint.h>

typedef __bf16 bf16x8 __attribute__((ext_vector_type(8)));
typedef float f32x4 __attribute__((ext_vector_type(4)));
typedef unsigned short u16;
typedef unsigned short u16x4  __attribute__((ext_vector_type(4)));
typedef unsigned short u16x16 __attribute__((ext_vector_type(16)));

#define B_  64
#define S_  256
#define I_  1024
#define H_  1024
#define NG  4096      /* 4*H */
#define M_  16384     /* S*B */

using gvoid_p = const __attribute__((address_space(1))) void*;
using lvoid_p = __attribute__((address_space(3))) void*;

__device__ __forceinline__ void gl_lds16(const void* g, void* l) {
  __builtin_amdgcn_global_load_lds((gvoid_p)g, (lvoid_p)l, 16, 0, 0);
}

__device__ __forceinline__ u16 f2bf(float f) {
  __hip_bfloat16 h = __float2bfloat16(f);
  union { __hip_bfloat16 h; u16 u; } c; c.h = h; return c.u;
}

// ---- fp32 -> bf16 converts -------------------------------------------------
// x: (B,S,I) fp32 -> xb row-major [(s*64+b)][I] bf16 (GEMM A layout)
__global__ void cvt_x(const float* __restrict__ x, u16* __restrict__ xb) {
  int bid = blockIdx.x;            // = s*64 + b
  int b = bid & 63, s = bid >> 6;
  int t = threadIdx.x;
  float4 v = ((const float4*)(x + (size_t)b * (S_ * I_) + (size_t)s * I_))[t];
  u16x4 o;
  o[0] = f2bf(v.x); o[1] = f2bf(v.y); o[2] = f2bf(v.z); o[3] = f2bf(v.w);
  ((u16x4*)(xb + (size_t)bid * I_))[t] = o;
}

__global__ void cvt_w(const float* __restrict__ w, u16* __restrict__ wb) {
  size_t i = ((size_t)blockIdx.x * 256 + threadIdx.x) * 4;
  float4 v = *(const float4*)(w + i);
  u16x4 o;
  o[0] = f2bf(v.x); o[1] = f2bf(v.y); o[2] = f2bf(v.z); o[3] = f2bf(v.w);
  *(u16x4*)(wb + i) = o;
}

// ---- big input GEMM: gx = X[16384][1024] * Wi[4096][1024]^T ----------------
// C written in lstm_rec fragment order: tile T=((s*64+w)*4+g)*1024,
// element (b, c16) at T + ((b>>2)&3)*256 + c16*16 + (b>>4)*4 + (b&3).
__global__ __launch_bounds__(256) void gemm_bt(const u16* __restrict__ A,
                                               const u16* __restrict__ BT,
                                               u16* __restrict__ C) {
  __shared__ u16 As[128 * 32];
  __shared__ u16 Bs[128 * 32];
  const int tid  = threadIdx.x;
  const int lane = tid & 63;
  const int wv   = tid >> 6;
  const int wm   = wv & 1, wn = wv >> 1;
  const int quad = lane >> 4, l16 = lane & 15;
  const int m0 = blockIdx.y * 128;
  const int n0 = blockIdx.x * 128;

  const int c0i = tid, c1i = tid + 256;
  const int ar0 = c0i >> 2, ak0 = (c0i & 3) * 8;
  const int ar1 = c1i >> 2, ak1 = (c1i & 3) * 8;

  f32x4 acc[4][4] = {};

  for (int kt = 0; kt < 32; ++kt) {
    const int k0 = kt * 32;
    __syncthreads();
    gl_lds16(A + (size_t)(m0 + ar0) * I_ + k0 + ak0, &As[c0i * 8]);
    gl_lds16(A + (size_t)(m0 + ar1) * I_ + k0 + ak1, &As[c1i * 8]);
    gl_lds16(BT + (size_t)(n0 + ar0) * I_ + k0 + ak0, &Bs[c0i * 8]);
    gl_lds16(BT + (size_t)(n0 + ar1) * I_ + k0 + ak1, &Bs[c1i * 8]);
    __syncthreads();

    bf16x8 af[4], bfr[4];
#pragma unroll
    for (int mi = 0; mi < 4; ++mi)
      af[mi] = *(const bf16x8*)&As[(wm * 64 + mi * 16 + l16) * 32 + quad * 8];
#pragma unroll
    for (int ni = 0; ni < 4; ++ni)
      bfr[ni] = *(const bf16x8*)&Bs[(wn * 64 + ni * 16 + l16) * 32 + quad * 8];
#pragma unroll
    for (int mi = 0; mi < 4; ++mi)
#pragma unroll
      for (int ni = 0; ni < 4; ++ni)
        acc[mi][ni] = __builtin_amdgcn_mfma_f32_16x16x32_bf16(af[mi], bfr[ni], acc[mi][ni], 0, 0, 0);
  }

  // epilogue: row = m0 + wm*64 + mi*16 + quad*4 + r -> s = row>>6, b = row&63
  const int s_hi = (m0 >> 6) + wm;
#pragma unroll
  for (int ni = 0; ni < 4; ++ni) {
    const int colg = n0 + wn * 64 + ni * 16 + l16;
    const int g = colg >> 10, hcol = colg & 1023;
    const int w = hcol >> 4, c16 = hcol & 15;
    u16* base = C + (((size_t)(s_hi * 64 + w) * 4 + g) << 10) + (quad * 16 + c16) * 16;
    u16x16 sv;                       // true ext-vector: no aliasing UB
#pragma unroll
    for (int mi = 0; mi < 4; ++mi)
#pragma unroll
      for (int r = 0; r < 4; ++r)
        sv[mi * 4 + r] = f2bf(acc[mi][ni][r]);
    *(u16x16*)base = sv;             // 32B contiguous per lane
  }
}

// ---- persistent recurrent kernel (flag dataflow, no central barrier) -------
__device__ __forceinline__ void loadA(bf16x8* dst, const u16* hb, int kc, int col, int qoff) {
#pragma unroll
  for (int kk = 0; kk < 4; ++kk)
#pragma unroll
    for (int mi = 0; mi < 4; ++mi)
      dst[kk * 4 + mi] =
        *(const bf16x8*)(hb + (size_t)(mi * 16 + col) * H_ + kc * 128 + kk * 32 + qoff);
}

// 64 blocks x 256 thr. Block w owns h-cols [16w,16w+16) for all 4 gates.
__global__ __launch_bounds__(256, 1) void lstm_rec(
    const u16* __restrict__ whb,     // [4096][1024] bf16
    const u16* __restrict__ gxb,     // fragment-order tiles, see gemm_bt
    const float* __restrict__ b_i, const float* __restrict__ b_h,
    const float* __restrict__ h0, const float* __restrict__ c0,
    u16* hbuf,                       // [2][64][1024] bf16 (double buffer)
    float* __restrict__ out,         // hidden[64][256][1024], hN[64][1024], cN[64][1024]
    unsigned* flags) {               // [64], memset 0; flags[w]=t+1 => h(t) slice ready
  const int tid = threadIdx.x, lane = tid & 63, g = tid >> 6;
  const int quad = lane >> 4, col = lane & 15;
  const int qoff = quad * 8;
  const int w = blockIdx.x, jlo = w * 16;

  __shared__ float ex[4][64][17];    // gate exchange, padded

  // --- w_h B-fragments in registers for all 256 steps (128 VGPRs/lane) ---
  bf16x8 barr[32];
  {
    const u16* wrow = whb + (size_t)(g * H_ + jlo + col) * I_ + qoff;
#pragma unroll
    for (int kk = 0; kk < 32; ++kk)
      barr[kk] = *(const bf16x8*)(wrow + kk * 32);
  }
  const float biasv = b_i[g * H_ + jlo + col] + b_h[g * H_ + jlo + col];

  // --- per-thread elementwise ownership: row = batch, 4 contiguous cols ---
  const int erow = tid >> 2, ec0 = (tid & 3) * 4;
  float c_reg[4], h_reg[4];
  {
#pragma unroll
    for (int j = 0; j < 4; ++j) {
      const int cc = jlo + ec0 + j;
      c_reg[j] = c0[(size_t)erow * H_ + cc];
      h_reg[j] = h0[(size_t)erow * H_ + cc];
    }
    u16x4 hbv;
    hbv[0] = f2bf(h_reg[0]); hbv[1] = f2bf(h_reg[1]);
    hbv[2] = f2bf(h_reg[2]); hbv[3] = f2bf(h_reg[3]);
    *(u16x4*)(hbuf + (size_t)erow * H_ + jlo + ec0) = hbv;   // buffer 0
  }
  __syncthreads();                    // all slice stores drained (vmcnt) -> in local L2
  if (tid == 0) {
    __builtin_amdgcn_fence(__ATOMIC_RELEASE, "agent");         // L2 -> LLC
    __hip_atomic_store(&flags[w], 1u, __ATOMIC_RELAXED, __HIP_MEMORY_SCOPE_AGENT);
  }

#pragma unroll 1
  for (int s = 0; s < S_; ++s) {
    const u16* hb = hbuf + (size_t)(s & 1) * (B_ * H_);
    u16* hw = hbuf + (size_t)((s + 1) & 1) * (B_ * H_);

    // gx prefetch: 32B/lane coalesced, independent of flags -> hides under poll
    const u16* gp = gxb + (((size_t)(s * 64 + w) * 4 + g) << 10) + lane * 16;
    bf16x8 gx0 = *(const bf16x8*)gp;
    bf16x8 gx1 = *(const bf16x8*)(gp + 8);

    // --- dataflow wait: all 64 producer slices of h(s) ready ---
    const unsigned tgt = (unsigned)(s + 1);
    while (1) {
      unsigned f = __hip_atomic_load(&flags[lane], __ATOMIC_RELAXED, __HIP_MEMORY_SCOPE_AGENT);
      if (__all((int)(f >= tgt))) break;
      __builtin_amdgcn_s_sleep(2);
    }
    __builtin_amdgcn_fence(__ATOMIC_ACQUIRE, "agent");   // invalidate caches before h reads

    // --- GEMV: direct global->VGPR A-fragments, register double-buffer ---
    f32x4 acc[4] = {};
    bf16x8 abuf[2][16];
    loadA(abuf[0], hb, 0, col, qoff);
#pragma unroll
    for (int kc = 0; kc < 8; ++kc) {
      if (kc < 7) loadA(abuf[(kc + 1) & 1], hb, kc + 1, col, qoff);
      const bf16x8* cu = abuf[kc & 1];
#pragma unroll
      for (int kk = 0; kk < 4; ++kk)
#pragma unroll
        for (int mi = 0; mi < 4; ++mi)
          acc[mi] = __builtin_amdgcn_mfma_f32_16x16x32_bf16(cu[kk * 4 + mi], barr[kc * 4 + kk], acc[mi], 0, 0, 0);
    }

    // --- wave-domain epilogue: bias + gx, activation, exchange via LDS ---
#pragma unroll
    for (int mi = 0; mi < 4; ++mi)
#pragma unroll
      for (int r = 0; r < 4; ++r) {
        const int j = mi * 4 + r;
        const float gxv = (j < 8) ? (float)gx0[j] : (float)gx1[j - 8];
        const float v = acc[mi][r] + biasv + gxv;
        const int b = mi * 16 + quad * 4 + r;
        if (g == 2) {  // tanh, overflow-safe fast path
          const float vc = fminf(fmaxf(v, -15.f), 15.f);
          const float e = __expf(2.f * vc);
          ex[g][b][col] = (e - 1.f) / (e + 1.f);
        } else {
          ex[g][b][col] = 1.f / (1.f + __expf(-v));
        }
      }
    __syncthreads();

    // --- thread-domain state update ---
    {
#pragma unroll
      for (int j = 0; j < 4; ++j) {
        const int cc = ec0 + j;
        const float iv = ex[0][erow][cc];
        const float fv = ex[1][erow][cc];
        const float gv = ex[2][erow][cc];
        const float ov = ex[3][erow][cc];
        const float c = fv * c_reg[j] + iv * gv;
        c_reg[j] = c;
        const float cc2 = fminf(fmaxf(c, -15.f), 15.f);
        const float e = __expf(2.f * cc2);
        h_reg[j] = ov * ((e - 1.f) / (e + 1.f));
      }
      f32x4 hv = { h_reg[0], h_reg[1], h_reg[2], h_reg[3] };
      __builtin_nontemporal_store(hv,
          (f32x4*)(out + (size_t)erow * (S_ * H_) + (size_t)s * H_ + jlo + ec0));
      u16x4 hbv;
      hbv[0] = f2bf(h_reg[0]); hbv[1] = f2bf(h_reg[1]);
      hbv[2] = f2bf(h_reg[2]); hbv[3] = f2bf(h_reg[3]);
      *(u16x4*)(hw + (size_t)erow * H_ + jlo + ec0) = hbv;
    }
    __syncthreads();                 // all waves' h-slice stores drained to L2
    if (tid == 0) {
      __builtin_amdgcn_fence(__ATOMIC_RELEASE, "agent");
      __hip_atomic_store(&flags[w], (unsigned)(s + 2), __ATOMIC_RELAXED, __HIP_MEMORY_SCOPE_AGENT);
    }
    // ex reuse protected by the __syncthreads above
  }

  // --- final hN, cN ---
  {
    const size_t base = (size_t)B_ * S_ * H_;
    f32x4 hv = { h_reg[0], h_reg[1], h_reg[2], h_reg[3] };
    f32x4 cv = { c_reg[0], c_reg[1], c_reg[2], c_reg[3] };
    *(f32x4*)(out + base + (size_t)erow * H_ + jlo + ec0) = hv;
    *(f32x4*)(out + base + (size_t)B_ * H_ + (size_t)erow * H_ + jlo + ec0) = cv;
  }
}

// ---- launch ----------------------------------------------------------------
extern "C" void kernel_launch(void* const* d_in, const int* in_sizes, int n_in,
                              void* d_out, int out_size, void* d_ws, size_t ws_size,
                              hipStream_t stream) {
  const float* x  = (const float*)d_in[0];
  const float* h0 = (const float*)d_in[1];
  const float* c0 = (const float*)d_in[2];
  const float* wi = (const float*)d_in[3];
  const float* wh = (const float*)d_in[4];
  const float* bi = (const float*)d_in[5];
  const float* bh = (const float*)d_in[6];
  float* out = (float*)d_out;

  char* ws = (char*)d_ws;
  u16* xb   = (u16*)(ws);                   //  33,554,432 B
  u16* wib  = (u16*)(ws + 33554432);        //   8,388,608 B
  u16* whb  = (u16*)(ws + 41943040);        //   8,388,608 B
  u16* gxb  = (u16*)(ws + 50331648);        // 134,217,728 B
  u16* hbuf = (u16*)(ws + 184549376);       //     262,144 B (double buffer)
  unsigned* flags = (unsigned*)(ws + 184811520);  // 256 B

  cvt_x<<<M_, 256, 0, stream>>>(x, xb);
  cvt_w<<<4096, 256, 0, stream>>>(wi, wib);
  cvt_w<<<4096, 256, 0, stream>>>(wh, whb);
  gemm_bt<<<dim3(NG / 128, M_ / 128), 256, 0, stream>>>(xb, wib, gxb);
  (void)hipMemsetAsync(flags, 0, 256, stream);

  void* args[] = { &whb, &gxb, &bi, &bh, &h0, &c0, &hbuf, &out, &flags };
  (void)hipLaunchCooperativeKernel((void*)lstm_rec, dim3(64), dim3(256), args, 0, stream);
}

// Round 5
// 4763.993 us; speedup vs baseline: 1.5522x; 1.5522x over previous
//
#include <hip/hip_runtime.h>
#include <hip/hip_bf16.h>
#include <stdint.h>

typedef __bf16 bf16x8 __attribute__((ext_vector_type(8)));
typedef float f32x4 __attribute__((ext_vector_type(4)));
typedef float f32x2 __attribute__((ext_vector_type(2)));
typedef unsigned short u16;
typedef unsigned short u16x4 __attribute__((ext_vector_type(4)));

#define B_  64
#define S_  256
#define I_  1024
#define H_  1024
#define NG  4096      /* 4*H */
#define M_  16384     /* S*B */

using gvoid_p = const __attribute__((address_space(1))) void*;
using lvoid_p = __attribute__((address_space(3))) void*;

__device__ __forceinline__ void gl_lds16(const void* g, void* l) {
  __builtin_amdgcn_global_load_lds((gvoid_p)g, (lvoid_p)l, 16, 0, 0);
}

__device__ __forceinline__ u16 f2bf(float f) {
  __hip_bfloat16 h = __float2bfloat16(f);
  union { __hip_bfloat16 h; u16 u; } c; c.h = h; return c.u;
}
__device__ __forceinline__ float bf2f(u16 u) {
  union { unsigned u; float f; } c; c.u = ((unsigned)u) << 16; return c.f;
}

// h loads from LLC (coherent, bypass L1/L2) — 16B as 2x8B relaxed-agent atomics
__device__ __forceinline__ bf16x8 loadA8(const u16* p) {
  union { unsigned long long u[2]; bf16x8 v; } c;
  c.u[0] = __hip_atomic_load((const unsigned long long*)p,
                             __ATOMIC_RELAXED, __HIP_MEMORY_SCOPE_AGENT);
  c.u[1] = __hip_atomic_load((const unsigned long long*)(p + 4),
                             __ATOMIC_RELAXED, __HIP_MEMORY_SCOPE_AGENT);
  return c.v;
}

// ---- fp32 -> bf16 converts -------------------------------------------------
__global__ void cvt_x(const float* __restrict__ x, u16* __restrict__ xb) {
  int bid = blockIdx.x;            // = s*64 + b
  int b = bid & 63, s = bid >> 6;
  int t = threadIdx.x;
  float4 v = ((const float4*)(x + (size_t)b * (S_ * I_) + (size_t)s * I_))[t];
  u16x4 o;
  o[0] = f2bf(v.x); o[1] = f2bf(v.y); o[2] = f2bf(v.z); o[3] = f2bf(v.w);
  ((u16x4*)(xb + (size_t)bid * I_))[t] = o;
}

__global__ void cvt_w(const float* __restrict__ w, u16* __restrict__ wb) {
  size_t i = ((size_t)blockIdx.x * 256 + threadIdx.x) * 4;
  float4 v = *(const float4*)(w + i);
  u16x4 o;
  o[0] = f2bf(v.x); o[1] = f2bf(v.y); o[2] = f2bf(v.z); o[3] = f2bf(v.w);
  *(u16x4*)(wb + i) = o;
}

// ---- big input GEMM: gx[16384][4096] = X * Wi^T (row-major C, R1-proven) ---
__global__ __launch_bounds__(256) void gemm_bt(const u16* __restrict__ A,
                                               const u16* __restrict__ BT,
                                               u16* __restrict__ C) {
  __shared__ u16 As[128 * 32];
  __shared__ u16 Bs[128 * 32];
  const int tid  = threadIdx.x;
  const int lane = tid & 63;
  const int wv   = tid >> 6;
  const int wm   = wv & 1, wn = wv >> 1;
  const int quad = lane >> 4, l16 = lane & 15;
  const int m0 = blockIdx.y * 128;
  const int n0 = blockIdx.x * 128;

  const int c0i = tid, c1i = tid + 256;
  const int ar0 = c0i >> 2, ak0 = (c0i & 3) * 8;
  const int ar1 = c1i >> 2, ak1 = (c1i & 3) * 8;

  f32x4 acc[4][4] = {};

  for (int kt = 0; kt < 32; ++kt) {
    const int k0 = kt * 32;
    __syncthreads();
    gl_lds16(A + (size_t)(m0 + ar0) * I_ + k0 + ak0, &As[c0i * 8]);
    gl_lds16(A + (size_t)(m0 + ar1) * I_ + k0 + ak1, &As[c1i * 8]);
    gl_lds16(BT + (size_t)(n0 + ar0) * I_ + k0 + ak0, &Bs[c0i * 8]);
    gl_lds16(BT + (size_t)(n0 + ar1) * I_ + k0 + ak1, &Bs[c1i * 8]);
    __syncthreads();

    bf16x8 af[4], bfr[4];
#pragma unroll
    for (int mi = 0; mi < 4; ++mi)
      af[mi] = *(const bf16x8*)&As[(wm * 64 + mi * 16 + l16) * 32 + quad * 8];
#pragma unroll
    for (int ni = 0; ni < 4; ++ni)
      bfr[ni] = *(const bf16x8*)&Bs[(wn * 64 + ni * 16 + l16) * 32 + quad * 8];
#pragma unroll
    for (int mi = 0; mi < 4; ++mi)
#pragma unroll
      for (int ni = 0; ni < 4; ++ni)
        acc[mi][ni] = __builtin_amdgcn_mfma_f32_16x16x32_bf16(af[mi], bfr[ni], acc[mi][ni], 0, 0, 0);
  }

#pragma unroll
  for (int mi = 0; mi < 4; ++mi)
#pragma unroll
    for (int ni = 0; ni < 4; ++ni) {
      const int col = n0 + wn * 64 + ni * 16 + l16;
#pragma unroll
      for (int r = 0; r < 4; ++r) {
        const int row = m0 + wm * 64 + mi * 16 + quad * 4 + r;
        C[(size_t)row * NG + col] = f2bf(acc[mi][ni][r]);
      }
    }
}

// ---- persistent recurrent kernel -------------------------------------------
// 128 blocks = 64 col-groups (w) x 2 batch-halves (bh). Block covers
// h-cols [16w,16w+16) for all 4 gates, batch rows [32bh, 32bh+32).
// Wave kq handles K-quarter [256kq, 256kq+256) for all 64 gate-cols;
// partials reduced via LDS. h exchanged via LLC (relaxed-agent atomics,
// NO cache-invalidating fences — w_h/gx stay warm in L2).
__global__ __launch_bounds__(256, 1) void lstm_rec(
    const u16* __restrict__ whb,     // [4096][1024] bf16
    const u16* __restrict__ gxb,     // [(s*64+b)][4096] bf16
    const float* __restrict__ b_i, const float* __restrict__ b_h,
    const float* __restrict__ h0, const float* __restrict__ c0,
    u16* hbuf,                       // [2][64][1024] bf16 (double buffer)
    float* __restrict__ out,         // hidden[64][256][1024], hN, cN
    unsigned* flags) {               // [2][64]; flags[bh][w]=t+1 => h(t) slice ready
  const int tid = threadIdx.x, lane = tid & 63, kq = tid >> 6;
  const int quad = lane >> 4, col = lane & 15;
  const int blk = blockIdx.x;
  const int w = blk & 63, bh = blk >> 6;   // (0,w),(1,w) adjacent-64 -> same XCD slice reuse
  const int jlo = w * 16;

  __shared__ float red[4][32][66];   // [kq][b'][gc'], stride 66 breaks bank conflicts

  // epilogue ownership: 512 outputs / 256 threads = 2 adjacent cols each
  const int eb = tid >> 3;           // b' 0..31
  const int ec = (tid & 7) * 2;      // hc0 (even)
  const int grow = bh * 32 + eb;     // global batch row

  float bias[4][2];
#pragma unroll
  for (int g = 0; g < 4; ++g)
#pragma unroll
    for (int j = 0; j < 2; ++j)
      bias[g][j] = b_i[g * H_ + jlo + ec + j] + b_h[g * H_ + jlo + ec + j];

  float cst[2], hl[2];
  {
    cst[0] = c0[(size_t)grow * H_ + jlo + ec];
    cst[1] = c0[(size_t)grow * H_ + jlo + ec + 1];
    hl[0]  = h0[(size_t)grow * H_ + jlo + ec];
    hl[1]  = h0[(size_t)grow * H_ + jlo + ec + 1];
    unsigned p = (unsigned)f2bf(hl[0]) | ((unsigned)f2bf(hl[1]) << 16);
    __hip_atomic_store((unsigned*)(hbuf + (size_t)grow * H_ + jlo + ec), p,
                       __ATOMIC_RELAXED, __HIP_MEMORY_SCOPE_AGENT);
  }
  __syncthreads();                   // drains vmcnt -> init h at LLC
  if (tid == 0)
    __hip_atomic_store(&flags[bh * 64 + w], 1u, __ATOMIC_RELEASE, __HIP_MEMORY_SCOPE_AGENT);

  // fragment base pointers
  const u16* wbase = whb + (size_t)(jlo + col) * I_ + kq * 256 + quad * 8;
  const unsigned* fl = flags + bh * 64;

#pragma unroll 1
  for (int s = 0; s < S_; ++s) {
    const u16* hb = hbuf + (size_t)(s & 1) * (B_ * H_);
    u16* hw = hbuf + (size_t)((s + 1) & 1) * (B_ * H_);

    // gx prefetch (plain, L2-warm): 4 x 4B per thread, coalesced
    const u16* gxp = gxb + (size_t)(s * 64 + grow) * NG + jlo + ec;
    unsigned gxu[4];
#pragma unroll
    for (int g = 0; g < 4; ++g)
      gxu[g] = *(const unsigned*)(gxp + g * H_);

    // dataflow wait: all 64 producers of this batch-half's h(s)
    const unsigned tgt = (unsigned)(s + 1);
    while (1) {
      unsigned f = __hip_atomic_load(fl + lane, __ATOMIC_RELAXED, __HIP_MEMORY_SCOPE_AGENT);
      if (__all((int)(f >= tgt))) break;
      __builtin_amdgcn_s_sleep(1);
    }
    asm volatile("" ::: "memory");   // compiler barrier: no hoist of h loads

    // K-quarter GEMV: A from LLC (coherent atomics), B from L2 (plain)
    const u16* habase = hb + (size_t)(bh * 32 + col) * H_ + kq * 256 + quad * 8;
    f32x4 acc[2][4] = {};
#pragma unroll
    for (int kt = 0; kt < 8; ++kt) {
      bf16x8 av[2], bv[4];
#pragma unroll
      for (int mi = 0; mi < 2; ++mi)
        av[mi] = loadA8(habase + (size_t)mi * 16 * H_ + kt * 32);
#pragma unroll
      for (int ni = 0; ni < 4; ++ni)
        bv[ni] = *(const bf16x8*)(wbase + (size_t)ni * H_ * I_ + kt * 32);
#pragma unroll
      for (int mi = 0; mi < 2; ++mi)
#pragma unroll
        for (int ni = 0; ni < 4; ++ni)
          acc[mi][ni] = __builtin_amdgcn_mfma_f32_16x16x32_bf16(av[mi], bv[ni], acc[mi][ni], 0, 0, 0);
    }

    // partials -> LDS
#pragma unroll
    for (int mi = 0; mi < 2; ++mi)
#pragma unroll
      for (int ni = 0; ni < 4; ++ni)
#pragma unroll
        for (int r = 0; r < 4; ++r)
          red[kq][mi * 16 + quad * 4 + r][ni * 16 + col] = acc[mi][ni][r];
    __syncthreads();

    // reduce 4 K-quarters + bias + gx, activations, c/h update
    float hnew[2];
#pragma unroll
    for (int j = 0; j < 2; ++j) {
      const int cc = ec + j;
      float gv[4];
#pragma unroll
      for (int g = 0; g < 4; ++g) {
        const int gc = g * 16 + cc;
        float v = red[0][eb][gc] + red[1][eb][gc] + red[2][eb][gc] + red[3][eb][gc];
        v += bias[g][j] + bf2f((u16)((gxu[g] >> (16 * j)) & 0xFFFFu));
        if (g == 2) {
          float vc = fminf(fmaxf(v, -15.f), 15.f);
          float e = __expf(2.f * vc);
          gv[g] = (e - 1.f) / (e + 1.f);
        } else {
          gv[g] = 1.f / (1.f + __expf(-v));
        }
      }
      float cn = gv[1] * cst[j] + gv[0] * gv[2];
      cst[j] = cn;
      float c2 = fminf(fmaxf(cn, -15.f), 15.f);
      float e = __expf(2.f * c2);
      hnew[j] = gv[3] * ((e - 1.f) / (e + 1.f));
    }
    hl[0] = hnew[0]; hl[1] = hnew[1];

    // h(s+1) -> LLC (coherent), out -> HBM (nontemporal, keep L2 clean)
    {
      unsigned p = (unsigned)f2bf(hnew[0]) | ((unsigned)f2bf(hnew[1]) << 16);
      __hip_atomic_store((unsigned*)(hw + (size_t)grow * H_ + jlo + ec), p,
                         __ATOMIC_RELAXED, __HIP_MEMORY_SCOPE_AGENT);
      f32x2 ov = { hnew[0], hnew[1] };
      __builtin_nontemporal_store(ov,
          (f32x2*)(out + ((size_t)grow * S_ + s) * H_ + jlo + ec));
    }
    __syncthreads();                 // drains vmcnt: all h stores at LLC; red reads done
    if (tid == 0)
      __hip_atomic_store(&flags[bh * 64 + w], (unsigned)(s + 2),
                         __ATOMIC_RELEASE, __HIP_MEMORY_SCOPE_AGENT);
  }

  // final hN, cN
  {
    const size_t base = (size_t)B_ * S_ * H_;
    f32x2 hv = { hl[0], hl[1] };
    f32x2 cv = { cst[0], cst[1] };
    *(f32x2*)(out + base + (size_t)grow * H_ + jlo + ec) = hv;
    *(f32x2*)(out + base + (size_t)B_ * H_ + (size_t)grow * H_ + jlo + ec) = cv;
  }
}

// ---- launch ----------------------------------------------------------------
extern "C" void kernel_launch(void* const* d_in, const int* in_sizes, int n_in,
                              void* d_out, int out_size, void* d_ws, size_t ws_size,
                              hipStream_t stream) {
  const float* x  = (const float*)d_in[0];
  const float* h0 = (const float*)d_in[1];
  const float* c0 = (const float*)d_in[2];
  const float* wi = (const float*)d_in[3];
  const float* wh = (const float*)d_in[4];
  const float* bi = (const float*)d_in[5];
  const float* bh = (const float*)d_in[6];
  float* out = (float*)d_out;

  char* ws = (char*)d_ws;
  u16* xb   = (u16*)(ws);                   //  33,554,432 B
  u16* wib  = (u16*)(ws + 33554432);        //   8,388,608 B
  u16* whb  = (u16*)(ws + 41943040);        //   8,388,608 B
  u16* gxb  = (u16*)(ws + 50331648);        // 134,217,728 B
  u16* hbuf = (u16*)(ws + 184549376);       //     262,144 B (double buffer)
  unsigned* flags = (unsigned*)(ws + 184811520);  // 512 B

  cvt_x<<<M_, 256, 0, stream>>>(x, xb);
  cvt_w<<<4096, 256, 0, stream>>>(wi, wib);
  cvt_w<<<4096, 256, 0, stream>>>(wh, whb);
  gemm_bt<<<dim3(NG / 128, M_ / 128), 256, 0, stream>>>(xb, wib, gxb);
  (void)hipMemsetAsync(flags, 0, 512, stream);

  void* args[] = { &whb, &gxb, &bi, &bh, &h0, &c0, &hbuf, &out, &flags };
  (void)hipLaunchCooperativeKernel((void*)lstm_rec, dim3(128), dim3(256), args, 0, stream);
}

// Round 6
// 1939.824 us; speedup vs baseline: 3.8120x; 2.4559x over previous
//
#include <hip/hip_runtime.h>
#include <hip/hip_bf16.h>
#include <stdint.h>

typedef __bf16 bf16x8 __attribute__((ext_vector_type(8)));
typedef float f32x4 __attribute__((ext_vector_type(4)));
typedef float f32x2 __attribute__((ext_vector_type(2)));
typedef unsigned short u16;
typedef unsigned short u16x4 __attribute__((ext_vector_type(4)));

#define B_  64
#define S_  256
#define I_  1024
#define H_  1024
#define NG  4096      /* 4*H */
#define M_  16384     /* S*B */

using gvoid_p = const __attribute__((address_space(1))) void*;
using lvoid_p = __attribute__((address_space(3))) void*;

__device__ __forceinline__ void gl_lds16(const void* g, void* l) {
  __builtin_amdgcn_global_load_lds((gvoid_p)g, (lvoid_p)l, 16, 0, 0);
}

__device__ __forceinline__ u16 f2bf(float f) {
  __hip_bfloat16 h = __float2bfloat16(f);
  union { __hip_bfloat16 h; u16 u; } c; c.h = h; return c.u;
}
__device__ __forceinline__ float bf2f(u16 u) {
  union { unsigned u; float f; } c; c.u = ((unsigned)u) << 16; return c.f;
}

// h loads from LLC (coherent, bypass L1/L2) — 16B as 2x8B relaxed-agent atomics
__device__ __forceinline__ bf16x8 loadA8(const u16* p) {
  union { unsigned long long u[2]; bf16x8 v; } c;
  c.u[0] = __hip_atomic_load((const unsigned long long*)p,
                             __ATOMIC_RELAXED, __HIP_MEMORY_SCOPE_AGENT);
  c.u[1] = __hip_atomic_load((const unsigned long long*)(p + 4),
                             __ATOMIC_RELAXED, __HIP_MEMORY_SCOPE_AGENT);
  return c.v;
}

// ---- fp32 -> bf16 converts -------------------------------------------------
__global__ void cvt_x(const float* __restrict__ x, u16* __restrict__ xb) {
  int bid = blockIdx.x;            // = s*64 + b
  int b = bid & 63, s = bid >> 6;
  int t = threadIdx.x;
  float4 v = ((const float4*)(x + (size_t)b * (S_ * I_) + (size_t)s * I_))[t];
  u16x4 o;
  o[0] = f2bf(v.x); o[1] = f2bf(v.y); o[2] = f2bf(v.z); o[3] = f2bf(v.w);
  ((u16x4*)(xb + (size_t)bid * I_))[t] = o;
}

__global__ void cvt_w(const float* __restrict__ w, u16* __restrict__ wb) {
  size_t i = ((size_t)blockIdx.x * 256 + threadIdx.x) * 4;
  float4 v = *(const float4*)(w + i);
  u16x4 o;
  o[0] = f2bf(v.x); o[1] = f2bf(v.y); o[2] = f2bf(v.z); o[3] = f2bf(v.w);
  *(u16x4*)(wb + i) = o;
}

// ---- big input GEMM: gx[16384][4096] = X * Wi^T (row-major C) --------------
__global__ __launch_bounds__(256) void gemm_bt(const u16* __restrict__ A,
                                               const u16* __restrict__ BT,
                                               u16* __restrict__ C) {
  __shared__ u16 As[128 * 32];
  __shared__ u16 Bs[128 * 32];
  const int tid  = threadIdx.x;
  const int lane = tid & 63;
  const int wv   = tid >> 6;
  const int wm   = wv & 1, wn = wv >> 1;
  const int quad = lane >> 4, l16 = lane & 15;
  const int m0 = blockIdx.y * 128;
  const int n0 = blockIdx.x * 128;

  const int c0i = tid, c1i = tid + 256;
  const int ar0 = c0i >> 2, ak0 = (c0i & 3) * 8;
  const int ar1 = c1i >> 2, ak1 = (c1i & 3) * 8;

  f32x4 acc[4][4] = {};

  for (int kt = 0; kt < 32; ++kt) {
    const int k0 = kt * 32;
    __syncthreads();
    gl_lds16(A + (size_t)(m0 + ar0) * I_ + k0 + ak0, &As[c0i * 8]);
    gl_lds16(A + (size_t)(m0 + ar1) * I_ + k0 + ak1, &As[c1i * 8]);
    gl_lds16(BT + (size_t)(n0 + ar0) * I_ + k0 + ak0, &Bs[c0i * 8]);
    gl_lds16(BT + (size_t)(n0 + ar1) * I_ + k0 + ak1, &Bs[c1i * 8]);
    __syncthreads();

    bf16x8 af[4], bfr[4];
#pragma unroll
    for (int mi = 0; mi < 4; ++mi)
      af[mi] = *(const bf16x8*)&As[(wm * 64 + mi * 16 + l16) * 32 + quad * 8];
#pragma unroll
    for (int ni = 0; ni < 4; ++ni)
      bfr[ni] = *(const bf16x8*)&Bs[(wn * 64 + ni * 16 + l16) * 32 + quad * 8];
#pragma unroll
    for (int mi = 0; mi < 4; ++mi)
#pragma unroll
      for (int ni = 0; ni < 4; ++ni)
        acc[mi][ni] = __builtin_amdgcn_mfma_f32_16x16x32_bf16(af[mi], bfr[ni], acc[mi][ni], 0, 0, 0);
  }

#pragma unroll
  for (int mi = 0; mi < 4; ++mi)
#pragma unroll
    for (int ni = 0; ni < 4; ++ni) {
      const int col = n0 + wn * 64 + ni * 16 + l16;
#pragma unroll
      for (int r = 0; r < 4; ++r) {
        const int row = m0 + wm * 64 + mi * 16 + quad * 4 + r;
        C[(size_t)row * NG + col] = f2bf(acc[mi][ni][r]);
      }
    }
}

// ---- persistent recurrent kernel -------------------------------------------
// 128 blocks = 64 col-groups (w) x 2 batch-halves (bh). Wave kq owns K-quarter.
// h exchanged via sc1 (LLC-coherent) relaxed atomics; flag visibility relies on
// __syncthreads' vmcnt(0) drain — NO release (avoids per-step buffer_wbl2!).
__global__ __launch_bounds__(256, 1) void lstm_rec(
    const u16* __restrict__ whb,     // [4096][1024] bf16
    const u16* __restrict__ gxb,     // [(s*64+b)][4096] bf16
    const float* __restrict__ b_i, const float* __restrict__ b_h,
    const float* __restrict__ h0, const float* __restrict__ c0,
    u16* hbuf,                       // [2][64][1024] bf16 (double buffer)
    float* __restrict__ out,         // hidden[64][256][1024], hN, cN
    unsigned* flags) {               // [2][64]; flags[bh][w]=t+1 => h(t) slice ready
  const int tid = threadIdx.x, lane = tid & 63, kq = tid >> 6;
  const int quad = lane >> 4, col = lane & 15;
  const int blk = blockIdx.x;
  const int w = blk & 63, bh = blk >> 6;
  const int jlo = w * 16;

  __shared__ float red[4][32][66];   // [kq][b'][gc'], stride 66 breaks bank conflicts

  const int eb = tid >> 3;           // b' 0..31
  const int ec = (tid & 7) * 2;      // hc0 (even)
  const int grow = bh * 32 + eb;     // global batch row

  float bias[4][2];
#pragma unroll
  for (int g = 0; g < 4; ++g)
#pragma unroll
    for (int j = 0; j < 2; ++j)
      bias[g][j] = b_i[g * H_ + jlo + ec + j] + b_h[g * H_ + jlo + ec + j];

  float cst[2], hl[2];
  {
    cst[0] = c0[(size_t)grow * H_ + jlo + ec];
    cst[1] = c0[(size_t)grow * H_ + jlo + ec + 1];
    hl[0]  = h0[(size_t)grow * H_ + jlo + ec];
    hl[1]  = h0[(size_t)grow * H_ + jlo + ec + 1];
    unsigned p = (unsigned)f2bf(hl[0]) | ((unsigned)f2bf(hl[1]) << 16);
    __hip_atomic_store((unsigned*)(hbuf + (size_t)grow * H_ + jlo + ec), p,
                       __ATOMIC_RELAXED, __HIP_MEMORY_SCOPE_AGENT);
  }
  __syncthreads();                   // vmcnt(0) drain: init h at LLC before flag
  if (tid == 0)
    __hip_atomic_store(&flags[bh * 64 + w], 1u, __ATOMIC_RELAXED, __HIP_MEMORY_SCOPE_AGENT);

  const u16* wbase = whb + (size_t)(jlo + col) * I_ + kq * 256 + quad * 8;
  const unsigned* fl = flags + bh * 64;

#pragma unroll 1
  for (int s = 0; s < S_; ++s) {
    const u16* hb = hbuf + (size_t)(s & 1) * (B_ * H_);
    u16* hw = hbuf + (size_t)((s + 1) & 1) * (B_ * H_);

    // gx prefetch (plain, L2-warm): 4 x 4B per thread, coalesced
    const u16* gxp = gxb + (size_t)(s * 64 + grow) * NG + jlo + ec;
    unsigned gxu[4];
#pragma unroll
    for (int g = 0; g < 4; ++g)
      gxu[g] = *(const unsigned*)(gxp + g * H_);

    // dataflow wait: wave 0 polls, others park at the barrier
    if (tid < 64) {
      const unsigned tgt = (unsigned)(s + 1);
      while (1) {
        unsigned f = __hip_atomic_load(fl + lane, __ATOMIC_RELAXED, __HIP_MEMORY_SCOPE_AGENT);
        if (__all((int)(f >= tgt))) break;
        __builtin_amdgcn_s_sleep(2);
      }
    }
    __syncthreads();

    // K-quarter GEMV: A from LLC (sc1 atomics), B from L2 (plain)
    const u16* habase = hb + (size_t)(bh * 32 + col) * H_ + kq * 256 + quad * 8;
    f32x4 acc[2][4] = {};
#pragma unroll
    for (int kt = 0; kt < 8; ++kt) {
      bf16x8 av[2], bv[4];
#pragma unroll
      for (int mi = 0; mi < 2; ++mi)
        av[mi] = loadA8(habase + (size_t)mi * 16 * H_ + kt * 32);
#pragma unroll
      for (int ni = 0; ni < 4; ++ni)
        bv[ni] = *(const bf16x8*)(wbase + (size_t)ni * H_ * I_ + kt * 32);
#pragma unroll
      for (int mi = 0; mi < 2; ++mi)
#pragma unroll
        for (int ni = 0; ni < 4; ++ni)
          acc[mi][ni] = __builtin_amdgcn_mfma_f32_16x16x32_bf16(av[mi], bv[ni], acc[mi][ni], 0, 0, 0);
    }

    // partials -> LDS
#pragma unroll
    for (int mi = 0; mi < 2; ++mi)
#pragma unroll
      for (int ni = 0; ni < 4; ++ni)
#pragma unroll
        for (int r = 0; r < 4; ++r)
          red[kq][mi * 16 + quad * 4 + r][ni * 16 + col] = acc[mi][ni][r];
    __syncthreads();

    // reduce 4 K-quarters + bias + gx, activations, c/h update
    float hnew[2];
#pragma unroll
    for (int j = 0; j < 2; ++j) {
      const int cc = ec + j;
      float gv[4];
#pragma unroll
      for (int g = 0; g < 4; ++g) {
        const int gc = g * 16 + cc;
        float v = red[0][eb][gc] + red[1][eb][gc] + red[2][eb][gc] + red[3][eb][gc];
        v += bias[g][j] + bf2f((u16)((gxu[g] >> (16 * j)) & 0xFFFFu));
        if (g == 2) {
          float vc = fminf(fmaxf(v, -15.f), 15.f);
          float e = __expf(2.f * vc);
          gv[g] = (e - 1.f) / (e + 1.f);
        } else {
          gv[g] = 1.f / (1.f + __expf(-v));
        }
      }
      float cn = gv[1] * cst[j] + gv[0] * gv[2];
      cst[j] = cn;
      float c2 = fminf(fmaxf(cn, -15.f), 15.f);
      float e = __expf(2.f * c2);
      hnew[j] = gv[3] * ((e - 1.f) / (e + 1.f));
    }
    hl[0] = hnew[0]; hl[1] = hnew[1];

    // h(s+1) -> LLC (sc1), out -> HBM (nontemporal)
    {
      unsigned p = (unsigned)f2bf(hnew[0]) | ((unsigned)f2bf(hnew[1]) << 16);
      __hip_atomic_store((unsigned*)(hw + (size_t)grow * H_ + jlo + ec), p,
                         __ATOMIC_RELAXED, __HIP_MEMORY_SCOPE_AGENT);
      f32x2 ov = { hnew[0], hnew[1] };
      __builtin_nontemporal_store(ov,
          (f32x2*)(out + ((size_t)grow * S_ + s) * H_ + jlo + ec));
    }
    __syncthreads();                 // vmcnt(0) drain: all h stores at LLC
    if (tid == 0)
      __hip_atomic_store(&flags[bh * 64 + w], (unsigned)(s + 2),
                         __ATOMIC_RELAXED, __HIP_MEMORY_SCOPE_AGENT);
  }

  // final hN, cN
  {
    const size_t base = (size_t)B_ * S_ * H_;
    f32x2 hv = { hl[0], hl[1] };
    f32x2 cv = { cst[0], cst[1] };
    *(f32x2*)(out + base + (size_t)grow * H_ + jlo + ec) = hv;
    *(f32x2*)(out + base + (size_t)B_ * H_ + (size_t)grow * H_ + jlo + ec) = cv;
  }
}

// ---- launch ----------------------------------------------------------------
extern "C" void kernel_launch(void* const* d_in, const int* in_sizes, int n_in,
                              void* d_out, int out_size, void* d_ws, size_t ws_size,
                              hipStream_t stream) {
  const float* x  = (const float*)d_in[0];
  const float* h0 = (const float*)d_in[1];
  const float* c0 = (const float*)d_in[2];
  const float* wi = (const float*)d_in[3];
  const float* wh = (const float*)d_in[4];
  const float* bi = (const float*)d_in[5];
  const float* bh = (const float*)d_in[6];
  float* out = (float*)d_out;

  char* ws = (char*)d_ws;
  u16* xb   = (u16*)(ws);                   //  33,554,432 B
  u16* wib  = (u16*)(ws + 33554432);        //   8,388,608 B
  u16* whb  = (u16*)(ws + 41943040);        //   8,388,608 B
  u16* gxb  = (u16*)(ws + 50331648);        // 134,217,728 B
  u16* hbuf = (u16*)(ws + 184549376);       //     262,144 B (double buffer)
  unsigned* flags = (unsigned*)(ws + 184811520);  // 512 B

  cvt_x<<<M_, 256, 0, stream>>>(x, xb);
  cvt_w<<<4096, 256, 0, stream>>>(wi, wib);
  cvt_w<<<4096, 256, 0, stream>>>(wh, whb);
  gemm_bt<<<dim3(NG / 128, M_ / 128), 256, 0, stream>>>(xb, wib, gxb);
  (void)hipMemsetAsync(flags, 0, 512, stream);

  void* args[] = { &whb, &gxb, &bi, &bh, &h0, &c0, &hbuf, &out, &flags };
  (void)hipLaunchCooperativeKernel((void*)lstm_rec, dim3(128), dim3(256), args, 0, stream);
}